// Round 15
// baseline (120.393 us; speedup 1.0000x reference)
//
#include <hip/hip_runtime.h>

// ---------------------------------------------------------------------------
// GCN 2-layer forward on MI355X — round 14: r12 revert + LDS-phase k_place.
//   r13 lesson: 8x GLOBAL seg re-reads at 196 blocks (occupancy-starved) cost
//   +14us. Same src-ordering now done from LDS: stage seg (16KB) once, 16
//   phase sweeps by src>>12 over LDS (~free). If ordering is neutral this is
//   r12 +- 1us; if the L2 phase-locality theory holds, gathers drop ~4-6us.
//   Rest identical to round 12 (100.6us): radix fill, MFMA GEMMs, 16/8-lane
//   gathers, bf16 H1/H2, CAP=64.
// ---------------------------------------------------------------------------

typedef short bf16x8 __attribute__((ext_vector_type(8)));
typedef float f32x4 __attribute__((ext_vector_type(4)));
typedef unsigned u32x4 __attribute__((ext_vector_type(4)));

static constexpr int CAP  = 64;      // bucket capacity per node (max deg << 64)
static constexpr int CAPB = 4096;    // edges per bin segment (mean 3072)

static __device__ __forceinline__ short f2bf(float f) {
  union { float f; unsigned u; } v; v.f = f;
  unsigned r = v.u + 0x7fff + ((v.u >> 16) & 1);   // round-to-nearest-even
  return (short)(r >> 16);
}
static __device__ __forceinline__ float bf2f(unsigned u16) {
  union { unsigned u; float f; } v; v.u = u16 << 16; return v.f;
}
// dinv from bucket cursor: deg = cursor - base, self-loop adds 1.
static __device__ __forceinline__ float dinv_of(int cur, int node) {
  return rsqrtf((float)(cur - (node << 6) + 1));
}

// --- init: W prep (WT[n][k] = bf16(W[k][n])) + zero bin counters -------------

__global__ __launch_bounds__(256) void k_init(const float* __restrict__ W1,
                                              const float* __restrict__ W2,
                                              unsigned short* __restrict__ WT1,
                                              unsigned short* __restrict__ WT2,
                                              int* __restrict__ gbin) {
  int t = blockIdx.x * 256 + threadIdx.x;
  if (t < 256) gbin[t] = 0;
  if (t < 128 * 128) {
    int k = t >> 7, nn = t & 127;
    WT1[nn * 128 + k] = (unsigned short)f2bf(W1[t]);
  }
  if (t < 128 * 64) {
    int k = t >> 6, nn = t & 63;
    WT2[nn * 128 + k] = (unsigned short)f2bf(W2[t]);
  }
}

// --- radix pass 1: bin edges by dst>>8 into per-bin segments -----------------
// One global atomicAdd per (block,bin); edge records packed (dst&255)|(src<<8).

__global__ __launch_bounds__(256) void k_bin(const int* __restrict__ src,
                                             const int* __restrict__ dst,
                                             int* __restrict__ gbin,
                                             unsigned* __restrict__ inter,
                                             int E, int nbins) {
  __shared__ int lcount[256];
  __shared__ int lcur[256];
  int t = threadIdx.x;
  lcount[t] = 0;
  __syncthreads();
  int base = blockIdx.x * 2048;
  int end = min(base + 2048, E);
  for (int i = base + t; i < end; i += 256)
    atomicAdd(&lcount[dst[i] >> 8], 1);
  __syncthreads();
  if (t < nbins && lcount[t] > 0) {
    int r = atomicAdd(&gbin[t], lcount[t]);
    lcur[t] = t * CAPB + r;
  }
  __syncthreads();
  for (int i = base + t; i < end; i += 256) {
    int d = dst[i], s = src[i];
    int bin = d >> 8;
    int pos = atomicAdd(&lcur[bin], 1);
    if (pos < (bin + 1) * CAPB)                       // stat. never
      inter[pos] = (unsigned)(d & 255) | ((unsigned)s << 8);
  }
}

// --- radix pass 2: place bin's edges into node buckets -----------------------
// Seg staged in LDS once; 16 phase sweeps by src>>12 (p>>20) order each bucket
// coarsely by src -> gathers sweep H1 in near-lockstep (~0.8MB per group).
// Also emits cursor[node] = node*64 + deg (covers empty nodes; no init pass).

__global__ __launch_bounds__(256) void k_place(const unsigned* __restrict__ inter,
                                               const int* __restrict__ gbin,
                                               unsigned short* __restrict__ col,
                                               int* __restrict__ cursor, int n) {
  __shared__ unsigned sseg[CAPB];
  __shared__ int lcur[256];
  int b = blockIdx.x, t = threadIdx.x;
  lcur[t] = 0;
  int cnt = min(gbin[b], CAPB);
  const unsigned* seg = inter + (size_t)b * CAPB;
  for (int i = t; i < cnt; i += 256) sseg[i] = seg[i];
  __syncthreads();
#pragma unroll 1
  for (unsigned ph = 0; ph < 16; ++ph) {           // src group = src>>12 (p>>20)
    for (int i = t; i < cnt; i += 256) {
      unsigned p = sseg[i];
      if ((p >> 20) == ph) {
        int dl = p & 255;
        int r = atomicAdd(&lcur[dl], 1);
        if (r < CAP)
          col[(size_t)(((b << 8) | dl) << 6) + r] = (unsigned short)(p >> 8);
      }
    }
    __syncthreads();                               // phase ordering in buckets
  }
  int node = (b << 8) | t;
  if (node < n) cursor[node] = (node << 6) + min(lcur[t], CAP);
}

// --- MFMA GEMM: Hout[r,:] = bf16(dinv[r] * (X[r, 0:128] @ W))  ---------------
// 256 threads = 4 waves x 16 rows (M-tile 64). WT (bf16 [BN][128]) in LDS,
// 272B row pitch. A-frag: lane = X[base+(lane&15)][(lane>>4)*8 + t*32 ..+8].
// C/D: col = lane&15, row = (lane>>4)*4 + reg.
template <int BN, bool ABF16>
static __device__ __forceinline__ void gemm_body(
    int bid, int tid, const void* __restrict__ Xv,
    const unsigned short* __restrict__ WT, const int* __restrict__ cursor,
    unsigned short* __restrict__ Hout, int n, unsigned char* WL) {
  constexpr int NT = BN / 16;
  constexpr int PITCH = 272;
  {
    const float4* srcw = (const float4*)WT;
#pragma unroll 4
    for (int q = tid; q < BN * 16; q += 256) {
      int r = q >> 4, c = q & 15;
      *(float4*)(&WL[r * PITCH + c * 16]) = srcw[q];
    }
  }
  __syncthreads();

  int wave = tid >> 6, lane = tid & 63;
  int lr = lane & 15, lg = lane >> 4;
  int row = bid * 64 + wave * 16 + lr;
  int arow = (row < n) ? row : (n - 1);

  bf16x8 af[4];
  if (ABF16) {
    const unsigned short* xr = (const unsigned short*)Xv + (size_t)arow * 128 + lg * 8;
#pragma unroll
    for (int t = 0; t < 4; ++t) af[t] = *(const bf16x8*)(xr + t * 32);
  } else {
    const float* xr = (const float*)Xv + (size_t)arow * 128 + lg * 8;
#pragma unroll
    for (int t = 0; t < 4; ++t) {
      float4 lo = *(const float4*)(xr + t * 32);
      float4 hi = *(const float4*)(xr + t * 32 + 4);
      bf16x8 a;
      a[0] = f2bf(lo.x); a[1] = f2bf(lo.y); a[2] = f2bf(lo.z); a[3] = f2bf(lo.w);
      a[4] = f2bf(hi.x); a[5] = f2bf(hi.y); a[6] = f2bf(hi.z); a[7] = f2bf(hi.w);
      af[t] = a;
    }
  }

  f32x4 acc[NT];
#pragma unroll
  for (int j = 0; j < NT; ++j) acc[j] = (f32x4){0.f, 0.f, 0.f, 0.f};

#pragma unroll
  for (int j = 0; j < NT; ++j) {
    const unsigned char* bp = &WL[(size_t)(j * 16 + lr) * PITCH + lg * 16];
#pragma unroll
    for (int t = 0; t < 4; ++t) {
      bf16x8 bfr = *(const bf16x8*)(bp + t * 64);
      acc[j] = __builtin_amdgcn_mfma_f32_16x16x32_bf16(af[t], bfr, acc[j], 0, 0, 0);
    }
  }

  int crow0 = bid * 64 + wave * 16 + lg * 4;
#pragma unroll
  for (int r = 0; r < 4; ++r) {
    int gr = crow0 + r;
    if (gr < n) {
      float sc = dinv_of(cursor[gr], gr);
#pragma unroll
      for (int j = 0; j < NT; ++j)
        Hout[(size_t)gr * BN + j * 16 + lr] = (unsigned short)f2bf(acc[j][r] * sc);
    }
  }
}

__global__ __launch_bounds__(256) void k_gemm1(const float* __restrict__ X,
                                               const unsigned short* __restrict__ WT,
                                               const int* __restrict__ cursor,
                                               unsigned short* __restrict__ Hout, int n) {
  __shared__ unsigned char WL[128 * 272];
  gemm_body<128, false>(blockIdx.x, threadIdx.x, X, WT, cursor, Hout, n, WL);
}

__global__ __launch_bounds__(256) void k_gemm2(const unsigned short* __restrict__ X,
                                               const unsigned short* __restrict__ WT,
                                               const int* __restrict__ cursor,
                                               unsigned short* __restrict__ Hout, int n) {
  __shared__ unsigned char WL[64 * 272];
  gemm_body<64, true>(blockIdx.x, threadIdx.x, X, WT, cursor, Hout, n, WL);
}

// --- fused gather layers -----------------------------------------------------
// H pre-scaled by dinv[row]; gather = pure row-sum of bf16 rows.

// Layer 1: 16-lane group per node (4 nodes/wave); lane reads 16B = dims
// [8*sub, 8*sub+8). relu fused, output packed bf16.
__global__ __launch_bounds__(256) void k_gather128(const int* __restrict__ cursor,
                                                   const unsigned short* __restrict__ col,
                                                   const unsigned* __restrict__ H1,
                                                   const float* __restrict__ b,
                                                   unsigned* __restrict__ OUT, int n) {
  int tid = threadIdx.x;
  int lane = tid & 63;
  int g = lane >> 4, sub = lane & 15;
  int node = blockIdx.x * 16 + (tid >> 6) * 4 + g;
  if (node >= n) return;
  int e0 = node << 6;
  int cur = cursor[node];
  float di = dinv_of(cur, node);
  int e1 = min(cur, e0 + CAP);
  const u32x4* H4 = (const u32x4*)H1;   // row stride 16 u32x4
  float acc[8];
#pragma unroll
  for (int j = 0; j < 8; ++j) acc[j] = 0.f;
  int e = e0;
  for (; e + 4 <= e1; e += 4) {
    u32x4 v0 = H4[(size_t)col[e] * 16 + sub];
    u32x4 v1 = H4[(size_t)col[e + 1] * 16 + sub];
    u32x4 v2 = H4[(size_t)col[e + 2] * 16 + sub];
    u32x4 v3 = H4[(size_t)col[e + 3] * 16 + sub];
#pragma unroll
    for (int j = 0; j < 4; ++j) {
      acc[2 * j]     += (bf2f(v0[j] & 0xffff) + bf2f(v1[j] & 0xffff)) +
                        (bf2f(v2[j] & 0xffff) + bf2f(v3[j] & 0xffff));
      acc[2 * j + 1] += (bf2f(v0[j] >> 16) + bf2f(v1[j] >> 16)) +
                        (bf2f(v2[j] >> 16) + bf2f(v3[j] >> 16));
    }
  }
  for (; e < e1; ++e) {
    u32x4 v0 = H4[(size_t)col[e] * 16 + sub];
#pragma unroll
    for (int j = 0; j < 4; ++j) {
      acc[2 * j]     += bf2f(v0[j] & 0xffff);
      acc[2 * j + 1] += bf2f(v0[j] >> 16);
    }
  }
  u32x4 vs = H4[(size_t)node * 16 + sub];
  float4 b0 = *(const float4*)(b + 8 * sub);
  float4 b1 = *(const float4*)(b + 8 * sub + 4);
  float bb[8] = {b0.x, b0.y, b0.z, b0.w, b1.x, b1.y, b1.z, b1.w};
  u32x4 o;
#pragma unroll
  for (int j = 0; j < 4; ++j) {
    float vx = fmaxf((acc[2 * j] + bf2f(vs[j] & 0xffff)) * di + bb[2 * j], 0.f);
    float vy = fmaxf((acc[2 * j + 1] + bf2f(vs[j] >> 16)) * di + bb[2 * j + 1], 0.f);
    o[j] = (unsigned)(unsigned short)f2bf(vx) |
           ((unsigned)(unsigned short)f2bf(vy) << 16);
  }
  ((u32x4*)OUT)[(size_t)node * 16 + sub] = o;
}

// Layer 2: 8-lane group per node (8 nodes/wave); lane reads 16B = dims
// [8*sub, 8*sub+8). bias + log_softmax fused, fp32 out.
__global__ __launch_bounds__(256) void k_gather64_lsm(const int* __restrict__ cursor,
                                                      const unsigned short* __restrict__ col,
                                                      const unsigned* __restrict__ H2,
                                                      const float* __restrict__ b,
                                                      float* __restrict__ OUT, int n) {
  int tid = threadIdx.x;
  int lane = tid & 63;
  int g = lane >> 3, sub = lane & 7;
  int node = blockIdx.x * 32 + (tid >> 6) * 8 + g;
  if (node >= n) return;
  int e0 = node << 6;
  int cur = cursor[node];
  float di = dinv_of(cur, node);
  int e1 = min(cur, e0 + CAP);
  const u32x4* H4 = (const u32x4*)H2;   // row stride 8 u32x4
  float acc[8];
#pragma unroll
  for (int j = 0; j < 8; ++j) acc[j] = 0.f;
  int e = e0;
  for (; e + 4 <= e1; e += 4) {
    u32x4 v0 = H4[(size_t)col[e] * 8 + sub];
    u32x4 v1 = H4[(size_t)col[e + 1] * 8 + sub];
    u32x4 v2 = H4[(size_t)col[e + 2] * 8 + sub];
    u32x4 v3 = H4[(size_t)col[e + 3] * 8 + sub];
#pragma unroll
    for (int j = 0; j < 4; ++j) {
      acc[2 * j]     += (bf2f(v0[j] & 0xffff) + bf2f(v1[j] & 0xffff)) +
                        (bf2f(v2[j] & 0xffff) + bf2f(v3[j] & 0xffff));
      acc[2 * j + 1] += (bf2f(v0[j] >> 16) + bf2f(v1[j] >> 16)) +
                        (bf2f(v2[j] >> 16) + bf2f(v3[j] >> 16));
    }
  }
  for (; e < e1; ++e) {
    u32x4 v0 = H4[(size_t)col[e] * 8 + sub];
#pragma unroll
    for (int j = 0; j < 4; ++j) {
      acc[2 * j]     += bf2f(v0[j] & 0xffff);
      acc[2 * j + 1] += bf2f(v0[j] >> 16);
    }
  }
  u32x4 vs = H4[(size_t)node * 8 + sub];
  float4 b0 = *(const float4*)(b + 8 * sub);
  float4 b1 = *(const float4*)(b + 8 * sub + 4);
  float bb[8] = {b0.x, b0.y, b0.z, b0.w, b1.x, b1.y, b1.z, b1.w};
  float v[8];
#pragma unroll
  for (int j = 0; j < 4; ++j) {
    v[2 * j]     = (acc[2 * j] + bf2f(vs[j] & 0xffff)) * di + bb[2 * j];
    v[2 * j + 1] = (acc[2 * j + 1] + bf2f(vs[j] >> 16)) * di + bb[2 * j + 1];
  }
  float m = v[0];
#pragma unroll
  for (int j = 1; j < 8; ++j) m = fmaxf(m, v[j]);
#pragma unroll
  for (int off = 1; off < 8; off <<= 1) m = fmaxf(m, __shfl_xor(m, off));
  float s = 0.f;
#pragma unroll
  for (int j = 0; j < 8; ++j) s += expf(v[j] - m);
#pragma unroll
  for (int off = 1; off < 8; off <<= 1) s += __shfl_xor(s, off);
  float ls = logf(s) + m;
  float4 o0 = make_float4(v[0] - ls, v[1] - ls, v[2] - ls, v[3] - ls);
  float4 o1 = make_float4(v[4] - ls, v[5] - ls, v[6] - ls, v[7] - ls);
  float* op = OUT + (size_t)node * 64 + 8 * sub;
  *(float4*)op = o0;
  *(float4*)(op + 4) = o1;
}

// ---------------------------------------------------------------------------

extern "C" void kernel_launch(void* const* d_in, const int* in_sizes, int n_in,
                              void* d_out, int out_size, void* d_ws, size_t ws_size,
                              hipStream_t stream) {
  const float* x  = (const float*)d_in[0];
  const int*   ei = (const int*)d_in[1];
  const float* W1 = (const float*)d_in[2];
  const float* b1 = (const float*)d_in[3];
  const float* W2 = (const float*)d_in[4];
  const float* b2 = (const float*)d_in[5];
  float* out = (float*)d_out;

  const int N = in_sizes[0] / 128;  // 50000
  const int E = in_sizes[1] / 2;    // 600000
  const int* src = ei;
  const int* dst = ei + E;
  const int NBINS = (N + 255) >> 8; // 196

  // Workspace layout (~42 MB; all regions 16B aligned).
  int*            gbin   = (int*)d_ws;                    // 256
  int*            cursor = gbin + 256;                    // N
  unsigned short* WT1    = (unsigned short*)(cursor + N); // 128*128 bf16
  unsigned short* WT2    = WT1 + 128 * 128;               // 64*128 bf16
  unsigned*       inter  = (unsigned*)(WT2 + 64 * 128);   // NBINS*CAPB u32
  unsigned short* col    = (unsigned short*)(inter + (size_t)NBINS * CAPB); // N*CAP
  unsigned short* bufH1  = col + (size_t)N * CAP;         // N*128 bf16 (h1)
  unsigned short* bufR   = bufH1 + (size_t)N * 128;       // N*128 bf16 (relu)
  unsigned short* bufH2  = bufR + (size_t)N * 128;        // N*64 bf16 (h2)

  // --- init (W prep + zero bins) -> radix fill (2 passes, LDS-phase order) ---
  k_init<<<64, 256, 0, stream>>>(W1, W2, WT1, WT2, gbin);
  k_bin<<<(E + 2047) / 2048, 256, 0, stream>>>(src, dst, gbin, inter, E, NBINS);
  k_place<<<NBINS, 256, 0, stream>>>(inter, gbin, col, cursor, N);

  const int gemm_grid = (N + 63) / 64;  // 782

  // --- layer 1 ---
  k_gemm1<<<gemm_grid, 256, 0, stream>>>(x, WT1, cursor, bufH1, N);
  k_gather128<<<(N + 15) / 16, 256, 0, stream>>>(cursor, col,
                                                 (const unsigned*)bufH1, b1,
                                                 (unsigned*)bufR, N);

  // --- layer 2 ---
  k_gemm2<<<gemm_grid, 256, 0, stream>>>(bufR, WT2, cursor, bufH2, N);
  k_gather64_lsm<<<(N + 31) / 32, 256, 0, stream>>>(cursor, col,
                                                    (const unsigned*)bufH2, b2,
                                                    out, N);
}

// Round 16
// 100.606 us; speedup vs baseline: 1.1967x; 1.1967x over previous
//
#include <hip/hip_runtime.h>

// ---------------------------------------------------------------------------
// GCN 2-layer forward on MI355X — round 15: exact revert to round-12 optimum.
//   (100.6us measured). src-ordering refuted twice (r13: +14us global rescan;
//   r14: +20us LDS-phase — 196-block producer can't amortize any ordering
//   cost; gathers already ~85% of achievable random-gather fetch BW).
//   Structure: radix fill (k_bin ~57k fabric atomics + k_place LDS atomics),
//   MFMA GEMMs (dinv fused, bf16 out), 16/8-lane-group gathers, CAP=64.
// ---------------------------------------------------------------------------

typedef short bf16x8 __attribute__((ext_vector_type(8)));
typedef float f32x4 __attribute__((ext_vector_type(4)));
typedef unsigned u32x4 __attribute__((ext_vector_type(4)));

static constexpr int CAP  = 64;      // bucket capacity per node (max deg << 64)
static constexpr int CAPB = 4096;    // edges per bin segment (mean 3072)

static __device__ __forceinline__ short f2bf(float f) {
  union { float f; unsigned u; } v; v.f = f;
  unsigned r = v.u + 0x7fff + ((v.u >> 16) & 1);   // round-to-nearest-even
  return (short)(r >> 16);
}
static __device__ __forceinline__ float bf2f(unsigned u16) {
  union { unsigned u; float f; } v; v.u = u16 << 16; return v.f;
}
// dinv from bucket cursor: deg = cursor - base, self-loop adds 1.
static __device__ __forceinline__ float dinv_of(int cur, int node) {
  return rsqrtf((float)(cur - (node << 6) + 1));
}

// --- init: W prep (WT[n][k] = bf16(W[k][n])) + zero bin counters -------------

__global__ __launch_bounds__(256) void k_init(const float* __restrict__ W1,
                                              const float* __restrict__ W2,
                                              unsigned short* __restrict__ WT1,
                                              unsigned short* __restrict__ WT2,
                                              int* __restrict__ gbin) {
  int t = blockIdx.x * 256 + threadIdx.x;
  if (t < 256) gbin[t] = 0;
  if (t < 128 * 128) {
    int k = t >> 7, nn = t & 127;
    WT1[nn * 128 + k] = (unsigned short)f2bf(W1[t]);
  }
  if (t < 128 * 64) {
    int k = t >> 6, nn = t & 63;
    WT2[nn * 128 + k] = (unsigned short)f2bf(W2[t]);
  }
}

// --- radix pass 1: bin edges by dst>>8 into per-bin segments -----------------
// One global atomicAdd per (block,bin); edge records packed (dst&255)|(src<<8).

__global__ __launch_bounds__(256) void k_bin(const int* __restrict__ src,
                                             const int* __restrict__ dst,
                                             int* __restrict__ gbin,
                                             unsigned* __restrict__ inter,
                                             int E, int nbins) {
  __shared__ int lcount[256];
  __shared__ int lcur[256];
  int t = threadIdx.x;
  lcount[t] = 0;
  __syncthreads();
  int base = blockIdx.x * 2048;
  int end = min(base + 2048, E);
  for (int i = base + t; i < end; i += 256)
    atomicAdd(&lcount[dst[i] >> 8], 1);
  __syncthreads();
  if (t < nbins && lcount[t] > 0) {
    int r = atomicAdd(&gbin[t], lcount[t]);
    lcur[t] = t * CAPB + r;
  }
  __syncthreads();
  for (int i = base + t; i < end; i += 256) {
    int d = dst[i], s = src[i];
    int bin = d >> 8;
    int pos = atomicAdd(&lcur[bin], 1);
    if (pos < (bin + 1) * CAPB)                       // stat. never
      inter[pos] = (unsigned)(d & 255) | ((unsigned)s << 8);
  }
}

// --- radix pass 2: place bin's edges into node buckets (LDS atomics only) ----
// Also emits cursor[node] = node*64 + deg (covers empty nodes; no init pass).

__global__ __launch_bounds__(256) void k_place(const unsigned* __restrict__ inter,
                                               const int* __restrict__ gbin,
                                               unsigned short* __restrict__ col,
                                               int* __restrict__ cursor, int n) {
  __shared__ int lcur[256];
  int b = blockIdx.x, t = threadIdx.x;
  lcur[t] = 0;
  __syncthreads();
  int cnt = min(gbin[b], CAPB);
  const unsigned* seg = inter + (size_t)b * CAPB;
  for (int i = t; i < cnt; i += 256) {
    unsigned p = seg[i];
    int dl = p & 255;
    int r = atomicAdd(&lcur[dl], 1);
    if (r < CAP) col[(size_t)(((b << 8) | dl) << 6) + r] = (unsigned short)(p >> 8);
  }
  __syncthreads();
  int node = (b << 8) | t;
  if (node < n) cursor[node] = (node << 6) + min(lcur[t], CAP);
}

// --- MFMA GEMM: Hout[r,:] = bf16(dinv[r] * (X[r, 0:128] @ W))  ---------------
// 256 threads = 4 waves x 16 rows (M-tile 64). WT (bf16 [BN][128]) in LDS,
// 272B row pitch. A-frag: lane = X[base+(lane&15)][(lane>>4)*8 + t*32 ..+8].
// C/D: col = lane&15, row = (lane>>4)*4 + reg.
template <int BN, bool ABF16>
static __device__ __forceinline__ void gemm_body(
    int bid, int tid, const void* __restrict__ Xv,
    const unsigned short* __restrict__ WT, const int* __restrict__ cursor,
    unsigned short* __restrict__ Hout, int n, unsigned char* WL) {
  constexpr int NT = BN / 16;
  constexpr int PITCH = 272;
  {
    const float4* srcw = (const float4*)WT;
#pragma unroll 4
    for (int q = tid; q < BN * 16; q += 256) {
      int r = q >> 4, c = q & 15;
      *(float4*)(&WL[r * PITCH + c * 16]) = srcw[q];
    }
  }
  __syncthreads();

  int wave = tid >> 6, lane = tid & 63;
  int lr = lane & 15, lg = lane >> 4;
  int row = bid * 64 + wave * 16 + lr;
  int arow = (row < n) ? row : (n - 1);

  bf16x8 af[4];
  if (ABF16) {
    const unsigned short* xr = (const unsigned short*)Xv + (size_t)arow * 128 + lg * 8;
#pragma unroll
    for (int t = 0; t < 4; ++t) af[t] = *(const bf16x8*)(xr + t * 32);
  } else {
    const float* xr = (const float*)Xv + (size_t)arow * 128 + lg * 8;
#pragma unroll
    for (int t = 0; t < 4; ++t) {
      float4 lo = *(const float4*)(xr + t * 32);
      float4 hi = *(const float4*)(xr + t * 32 + 4);
      bf16x8 a;
      a[0] = f2bf(lo.x); a[1] = f2bf(lo.y); a[2] = f2bf(lo.z); a[3] = f2bf(lo.w);
      a[4] = f2bf(hi.x); a[5] = f2bf(hi.y); a[6] = f2bf(hi.z); a[7] = f2bf(hi.w);
      af[t] = a;
    }
  }

  f32x4 acc[NT];
#pragma unroll
  for (int j = 0; j < NT; ++j) acc[j] = (f32x4){0.f, 0.f, 0.f, 0.f};

#pragma unroll
  for (int j = 0; j < NT; ++j) {
    const unsigned char* bp = &WL[(size_t)(j * 16 + lr) * PITCH + lg * 16];
#pragma unroll
    for (int t = 0; t < 4; ++t) {
      bf16x8 bfr = *(const bf16x8*)(bp + t * 64);
      acc[j] = __builtin_amdgcn_mfma_f32_16x16x32_bf16(af[t], bfr, acc[j], 0, 0, 0);
    }
  }

  int crow0 = bid * 64 + wave * 16 + lg * 4;
#pragma unroll
  for (int r = 0; r < 4; ++r) {
    int gr = crow0 + r;
    if (gr < n) {
      float sc = dinv_of(cursor[gr], gr);
#pragma unroll
      for (int j = 0; j < NT; ++j)
        Hout[(size_t)gr * BN + j * 16 + lr] = (unsigned short)f2bf(acc[j][r] * sc);
    }
  }
}

__global__ __launch_bounds__(256) void k_gemm1(const float* __restrict__ X,
                                               const unsigned short* __restrict__ WT,
                                               const int* __restrict__ cursor,
                                               unsigned short* __restrict__ Hout, int n) {
  __shared__ unsigned char WL[128 * 272];
  gemm_body<128, false>(blockIdx.x, threadIdx.x, X, WT, cursor, Hout, n, WL);
}

__global__ __launch_bounds__(256) void k_gemm2(const unsigned short* __restrict__ X,
                                               const unsigned short* __restrict__ WT,
                                               const int* __restrict__ cursor,
                                               unsigned short* __restrict__ Hout, int n) {
  __shared__ unsigned char WL[64 * 272];
  gemm_body<64, true>(blockIdx.x, threadIdx.x, X, WT, cursor, Hout, n, WL);
}

// --- fused gather layers -----------------------------------------------------
// H pre-scaled by dinv[row]; gather = pure row-sum of bf16 rows.

// Layer 1: 16-lane group per node (4 nodes/wave); lane reads 16B = dims
// [8*sub, 8*sub+8). relu fused, output packed bf16.
__global__ __launch_bounds__(256) void k_gather128(const int* __restrict__ cursor,
                                                   const unsigned short* __restrict__ col,
                                                   const unsigned* __restrict__ H1,
                                                   const float* __restrict__ b,
                                                   unsigned* __restrict__ OUT, int n) {
  int tid = threadIdx.x;
  int lane = tid & 63;
  int g = lane >> 4, sub = lane & 15;
  int node = blockIdx.x * 16 + (tid >> 6) * 4 + g;
  if (node >= n) return;
  int e0 = node << 6;
  int cur = cursor[node];
  float di = dinv_of(cur, node);
  int e1 = min(cur, e0 + CAP);
  const u32x4* H4 = (const u32x4*)H1;   // row stride 16 u32x4
  float acc[8];
#pragma unroll
  for (int j = 0; j < 8; ++j) acc[j] = 0.f;
  int e = e0;
  for (; e + 4 <= e1; e += 4) {
    u32x4 v0 = H4[(size_t)col[e] * 16 + sub];
    u32x4 v1 = H4[(size_t)col[e + 1] * 16 + sub];
    u32x4 v2 = H4[(size_t)col[e + 2] * 16 + sub];
    u32x4 v3 = H4[(size_t)col[e + 3] * 16 + sub];
#pragma unroll
    for (int j = 0; j < 4; ++j) {
      acc[2 * j]     += (bf2f(v0[j] & 0xffff) + bf2f(v1[j] & 0xffff)) +
                        (bf2f(v2[j] & 0xffff) + bf2f(v3[j] & 0xffff));
      acc[2 * j + 1] += (bf2f(v0[j] >> 16) + bf2f(v1[j] >> 16)) +
                        (bf2f(v2[j] >> 16) + bf2f(v3[j] >> 16));
    }
  }
  for (; e < e1; ++e) {
    u32x4 v0 = H4[(size_t)col[e] * 16 + sub];
#pragma unroll
    for (int j = 0; j < 4; ++j) {
      acc[2 * j]     += bf2f(v0[j] & 0xffff);
      acc[2 * j + 1] += bf2f(v0[j] >> 16);
    }
  }
  u32x4 vs = H4[(size_t)node * 16 + sub];
  float4 b0 = *(const float4*)(b + 8 * sub);
  float4 b1 = *(const float4*)(b + 8 * sub + 4);
  float bb[8] = {b0.x, b0.y, b0.z, b0.w, b1.x, b1.y, b1.z, b1.w};
  u32x4 o;
#pragma unroll
  for (int j = 0; j < 4; ++j) {
    float vx = fmaxf((acc[2 * j] + bf2f(vs[j] & 0xffff)) * di + bb[2 * j], 0.f);
    float vy = fmaxf((acc[2 * j + 1] + bf2f(vs[j] >> 16)) * di + bb[2 * j + 1], 0.f);
    o[j] = (unsigned)(unsigned short)f2bf(vx) |
           ((unsigned)(unsigned short)f2bf(vy) << 16);
  }
  ((u32x4*)OUT)[(size_t)node * 16 + sub] = o;
}

// Layer 2: 8-lane group per node (8 nodes/wave); lane reads 16B = dims
// [8*sub, 8*sub+8). bias + log_softmax fused, fp32 out.
__global__ __launch_bounds__(256) void k_gather64_lsm(const int* __restrict__ cursor,
                                                      const unsigned short* __restrict__ col,
                                                      const unsigned* __restrict__ H2,
                                                      const float* __restrict__ b,
                                                      float* __restrict__ OUT, int n) {
  int tid = threadIdx.x;
  int lane = tid & 63;
  int g = lane >> 3, sub = lane & 7;
  int node = blockIdx.x * 32 + (tid >> 6) * 8 + g;
  if (node >= n) return;
  int e0 = node << 6;
  int cur = cursor[node];
  float di = dinv_of(cur, node);
  int e1 = min(cur, e0 + CAP);
  const u32x4* H4 = (const u32x4*)H2;   // row stride 8 u32x4
  float acc[8];
#pragma unroll
  for (int j = 0; j < 8; ++j) acc[j] = 0.f;
  int e = e0;
  for (; e + 4 <= e1; e += 4) {
    u32x4 v0 = H4[(size_t)col[e] * 8 + sub];
    u32x4 v1 = H4[(size_t)col[e + 1] * 8 + sub];
    u32x4 v2 = H4[(size_t)col[e + 2] * 8 + sub];
    u32x4 v3 = H4[(size_t)col[e + 3] * 8 + sub];
#pragma unroll
    for (int j = 0; j < 4; ++j) {
      acc[2 * j]     += (bf2f(v0[j] & 0xffff) + bf2f(v1[j] & 0xffff)) +
                        (bf2f(v2[j] & 0xffff) + bf2f(v3[j] & 0xffff));
      acc[2 * j + 1] += (bf2f(v0[j] >> 16) + bf2f(v1[j] >> 16)) +
                        (bf2f(v2[j] >> 16) + bf2f(v3[j] >> 16));
    }
  }
  for (; e < e1; ++e) {
    u32x4 v0 = H4[(size_t)col[e] * 8 + sub];
#pragma unroll
    for (int j = 0; j < 4; ++j) {
      acc[2 * j]     += bf2f(v0[j] & 0xffff);
      acc[2 * j + 1] += bf2f(v0[j] >> 16);
    }
  }
  u32x4 vs = H4[(size_t)node * 8 + sub];
  float4 b0 = *(const float4*)(b + 8 * sub);
  float4 b1 = *(const float4*)(b + 8 * sub + 4);
  float bb[8] = {b0.x, b0.y, b0.z, b0.w, b1.x, b1.y, b1.z, b1.w};
  float v[8];
#pragma unroll
  for (int j = 0; j < 4; ++j) {
    v[2 * j]     = (acc[2 * j] + bf2f(vs[j] & 0xffff)) * di + bb[2 * j];
    v[2 * j + 1] = (acc[2 * j + 1] + bf2f(vs[j] >> 16)) * di + bb[2 * j + 1];
  }
  float m = v[0];
#pragma unroll
  for (int j = 1; j < 8; ++j) m = fmaxf(m, v[j]);
#pragma unroll
  for (int off = 1; off < 8; off <<= 1) m = fmaxf(m, __shfl_xor(m, off));
  float s = 0.f;
#pragma unroll
  for (int j = 0; j < 8; ++j) s += expf(v[j] - m);
#pragma unroll
  for (int off = 1; off < 8; off <<= 1) s += __shfl_xor(s, off);
  float ls = logf(s) + m;
  float4 o0 = make_float4(v[0] - ls, v[1] - ls, v[2] - ls, v[3] - ls);
  float4 o1 = make_float4(v[4] - ls, v[5] - ls, v[6] - ls, v[7] - ls);
  float* op = OUT + (size_t)node * 64 + 8 * sub;
  *(float4*)op = o0;
  *(float4*)(op + 4) = o1;
}

// ---------------------------------------------------------------------------

extern "C" void kernel_launch(void* const* d_in, const int* in_sizes, int n_in,
                              void* d_out, int out_size, void* d_ws, size_t ws_size,
                              hipStream_t stream) {
  const float* x  = (const float*)d_in[0];
  const int*   ei = (const int*)d_in[1];
  const float* W1 = (const float*)d_in[2];
  const float* b1 = (const float*)d_in[3];
  const float* W2 = (const float*)d_in[4];
  const float* b2 = (const float*)d_in[5];
  float* out = (float*)d_out;

  const int N = in_sizes[0] / 128;  // 50000
  const int E = in_sizes[1] / 2;    // 600000
  const int* src = ei;
  const int* dst = ei + E;
  const int NBINS = (N + 255) >> 8; // 196

  // Workspace layout (~42 MB; all regions 16B aligned).
  int*            gbin   = (int*)d_ws;                    // 256
  int*            cursor = gbin + 256;                    // N
  unsigned short* WT1    = (unsigned short*)(cursor + N); // 128*128 bf16
  unsigned short* WT2    = WT1 + 128 * 128;               // 64*128 bf16
  unsigned*       inter  = (unsigned*)(WT2 + 64 * 128);   // NBINS*CAPB u32
  unsigned short* col    = (unsigned short*)(inter + (size_t)NBINS * CAPB); // N*CAP
  unsigned short* bufH1  = col + (size_t)N * CAP;         // N*128 bf16 (h1)
  unsigned short* bufR   = bufH1 + (size_t)N * 128;       // N*128 bf16 (relu)
  unsigned short* bufH2  = bufR + (size_t)N * 128;        // N*64 bf16 (h2)

  // --- init (W prep + zero bins) -> radix fill (2 passes) ---
  k_init<<<64, 256, 0, stream>>>(W1, W2, WT1, WT2, gbin);
  k_bin<<<(E + 2047) / 2048, 256, 0, stream>>>(src, dst, gbin, inter, E, NBINS);
  k_place<<<NBINS, 256, 0, stream>>>(inter, gbin, col, cursor, N);

  const int gemm_grid = (N + 63) / 64;  // 782

  // --- layer 1 ---
  k_gemm1<<<gemm_grid, 256, 0, stream>>>(x, WT1, cursor, bufH1, N);
  k_gather128<<<(N + 15) / 16, 256, 0, stream>>>(cursor, col,
                                                 (const unsigned*)bufH1, b1,
                                                 (unsigned*)bufR, N);

  // --- layer 2 ---
  k_gemm2<<<gemm_grid, 256, 0, stream>>>(bufR, WT2, cursor, bufH2, N);
  k_gather64_lsm<<<(N + 31) / 32, 256, 0, stream>>>(cursor, col,
                                                    (const unsigned*)bufH2, b2,
                                                    out, N);
}